// Round 1
// baseline (1089.419 us; speedup 1.0000x reference)
//
#include <hip/hip_runtime.h>
#include <cstdint>
#include <cstddef>

// Problem constants
// B=1, S=64, L_ENC=64, E=512, Z=512, H=1024, NL=2, V=32000
// Outputs (flat, in order): logits [64][32000], attn_out [64][2048], hT [2][1024], cT [2][1024]

#define OUT_LOGITS 0
#define OUT_ATTN   2048000           // 64*32000
#define OUT_HT     (2048000+131072)  // + 64*2048
#define OUT_CT     (OUT_HT+2048)

__device__ __forceinline__ float sigmoidf_(float x) { return 1.0f / (1.0f + expf(-x)); }

// ---------------------------------------------------------------------------
// K1: Gin0[t][r] = sum_k X[t][k] * W_ih0[r][k] + b_ih0[r] + b_hh0[r]
//     X[t] = concat(dec[t] (512), z (512))
// Tiled fp32 GEMM: 64 rows x 16 t per block, K-chunks of 64. Grid 256 blocks.
// ---------------------------------------------------------------------------
__global__ __launch_bounds__(256) void k_input_gemm(
    const float* __restrict__ dec,   // [64][512]
    const float* __restrict__ z,     // [512]
    const float* __restrict__ W_ih,  // [2][4096][1024] (layer 0 part)
    const float* __restrict__ b_ih,  // [2][4096]
    const float* __restrict__ b_hh,
    float* __restrict__ Gin0)        // [64][4096]
{
    __shared__ float Wt[64 * 65];
    __shared__ float Xt[16 * 65];
    const int rb = blockIdx.x & 63;    // 64 row-tiles
    const int tb = blockIdx.x >> 6;    // 4 t-tiles
    const int r0 = rb * 64, t0 = tb * 16;
    const int tid = threadIdx.x;
    const int vgrp = tid & 15;         // row group (4 rows)
    const int tt   = tid >> 4;         // local t (0..15)

    float acc[4] = {0.f, 0.f, 0.f, 0.f};

    for (int kk = 0; kk < 1024; kk += 64) {
        __syncthreads();
        #pragma unroll
        for (int i = 0; i < 16; ++i) {
            int e = tid + i * 256;
            int rr = e >> 6, cc = e & 63;
            Wt[rr * 65 + cc] = W_ih[(size_t)(r0 + rr) * 1024 + kk + cc];
        }
        #pragma unroll
        for (int i = 0; i < 4; ++i) {
            int e = tid + i * 256;
            int xt = e >> 6, cc = e & 63;
            int k = kk + cc;
            Xt[xt * 65 + cc] = (k < 512) ? dec[(size_t)(t0 + xt) * 512 + k] : z[k - 512];
        }
        __syncthreads();
        #pragma unroll 16
        for (int c = 0; c < 64; ++c) {
            float b = Xt[tt * 65 + c];
            #pragma unroll
            for (int m = 0; m < 4; ++m)
                acc[m] = fmaf(Wt[(vgrp * 4 + m) * 65 + c], b, acc[m]);
        }
    }
    const int r = r0 + vgrp * 4;
    float4 o;
    o.x = acc[0] + b_ih[r + 0] + b_hh[r + 0];
    o.y = acc[1] + b_ih[r + 1] + b_hh[r + 1];
    o.z = acc[2] + b_ih[r + 2] + b_hh[r + 2];
    o.w = acc[3] + b_ih[r + 3] + b_hh[r + 3];
    *(float4*)(Gin0 + (size_t)(t0 + tt) * 4096 + r) = o;
}

// ---------------------------------------------------------------------------
// Stage kernel: pipeline stage k computes layer0@t=k and layer1@t=k-1.
// Grid 512 blocks x 256 thr. Blocks 0..255 -> layer0 (4 units each, 1 wave/unit),
// blocks 256..511 -> layer1.
// outs (layer-1 h) written directly into d_out attn region, stride 2048 per t.
// ---------------------------------------------------------------------------
__global__ __launch_bounds__(256) void k_stage(
    int k,
    const float* __restrict__ W_ih,   // [2][4096][1024]
    const float* __restrict__ W_hh,   // [2][4096][1024]
    const float* __restrict__ b_ih,   // [2][4096]
    const float* __restrict__ b_hh,
    const float* __restrict__ h_init, // [2][1024]
    const float* __restrict__ c_init, // [2][1024]
    const float* __restrict__ Gin0,   // [64][4096]
    float* __restrict__ h0_hist,      // [64][1024]
    float* __restrict__ c0_state,     // [1024]
    float* __restrict__ c1_state,     // [1024]
    float* __restrict__ attn)         // d_out attn region [64][2048]
{
    __shared__ __align__(16) float hs[2048];
    const int blk   = blockIdx.x;
    const int layer = blk >> 8;
    const int tid   = threadIdx.x;
    const int lane  = tid & 63;
    const int u     = (blk & 255) * 4 + (tid >> 6);  // unit 0..1023

    if (layer == 0) {
        const int t = k;
        if (t >= 64) return;
        const float* hp = (t == 0) ? h_init : (h0_hist + (size_t)(t - 1) * 1024);
        for (int i = tid; i < 1024; i += 256) hs[i] = hp[i];
        __syncthreads();
        float g[4];
        #pragma unroll
        for (int q = 0; q < 4; ++q) {
            const float4* row = (const float4*)(W_hh + (size_t)(q * 1024 + u) * 1024);
            float acc = 0.f;
            #pragma unroll
            for (int it = 0; it < 4; ++it) {
                float4 w  = row[lane + 64 * it];
                float4 h4 = ((const float4*)hs)[lane + 64 * it];
                acc = fmaf(w.x, h4.x, fmaf(w.y, h4.y, fmaf(w.z, h4.z, fmaf(w.w, h4.w, acc))));
            }
            #pragma unroll
            for (int off = 32; off; off >>= 1) acc += __shfl_xor(acc, off, 64);
            g[q] = acc;
        }
        if (lane == 0) {
            const float* gin = Gin0 + (size_t)t * 4096;
            float gi = g[0] + gin[u];
            float gf = g[1] + gin[1024 + u];
            float gg = g[2] + gin[2048 + u];
            float go = g[3] + gin[3072 + u];
            float cp = (t == 0) ? c_init[u] : c0_state[u];
            float c  = sigmoidf_(gf) * cp + sigmoidf_(gi) * tanhf(gg);
            float h  = sigmoidf_(go) * tanhf(c);
            c0_state[u] = c;
            h0_hist[(size_t)t * 1024 + u] = h;
        }
    } else {
        const int t = k - 1;
        if (t < 0) return;
        const float* xin = h0_hist + (size_t)t * 1024;                       // input = h0_t
        const float* hp  = (t == 0) ? (h_init + 1024) : (attn + (size_t)(t - 1) * 2048);
        for (int i = tid; i < 1024; i += 256) { hs[i] = xin[i]; hs[1024 + i] = hp[i]; }
        __syncthreads();
        const float* Wi = W_ih + (size_t)4096 * 1024;
        const float* Wh = W_hh + (size_t)4096 * 1024;
        float g[4];
        #pragma unroll
        for (int q = 0; q < 4; ++q) {
            const float4* rowi = (const float4*)(Wi + (size_t)(q * 1024 + u) * 1024);
            const float4* rowh = (const float4*)(Wh + (size_t)(q * 1024 + u) * 1024);
            float acc = 0.f;
            #pragma unroll
            for (int it = 0; it < 4; ++it) {
                float4 w   = rowi[lane + 64 * it];
                float4 h4  = ((const float4*)hs)[lane + 64 * it];
                acc = fmaf(w.x, h4.x, fmaf(w.y, h4.y, fmaf(w.z, h4.z, fmaf(w.w, h4.w, acc))));
                float4 w2  = rowh[lane + 64 * it];
                float4 h42 = ((const float4*)(hs + 1024))[lane + 64 * it];
                acc = fmaf(w2.x, h42.x, fmaf(w2.y, h42.y, fmaf(w2.z, h42.z, fmaf(w2.w, h42.w, acc))));
            }
            #pragma unroll
            for (int off = 32; off; off >>= 1) acc += __shfl_xor(acc, off, 64);
            g[q] = acc + b_ih[4096 + q * 1024 + u] + b_hh[4096 + q * 1024 + u];
        }
        if (lane == 0) {
            float cp = (t == 0) ? c_init[1024 + u] : c1_state[u];
            float c  = sigmoidf_(g[1]) * cp + sigmoidf_(g[0]) * tanhf(g[2]);
            float h  = sigmoidf_(g[3]) * tanhf(c);
            c1_state[u] = c;
            attn[(size_t)t * 2048 + u] = h;   // outs[t]
        }
    }
}

// ---------------------------------------------------------------------------
// Attention: scores = outs @ enc^T, softmax over enc len, ctx = w @ enc.
// One block per t (64 blocks). outs read from / ctx written to attn region.
// ---------------------------------------------------------------------------
__global__ __launch_bounds__(256) void k_attn(
    const float* __restrict__ enc,   // [64][1024]
    float* __restrict__ attn)        // [64][2048], first half = outs
{
    __shared__ __align__(16) float os[1024];
    __shared__ float ss[64];
    __shared__ float ws[64];
    const int t = blockIdx.x;
    const int tid = threadIdx.x;
    const float* orow = attn + (size_t)t * 2048;
    for (int i = tid; i < 1024; i += 256) os[i] = orow[i];
    __syncthreads();
    const int wave = tid >> 6, lane = tid & 63;
    for (int li = 0; li < 16; ++li) {
        const int l = wave * 16 + li;
        const float4* er = (const float4*)(enc + (size_t)l * 1024);
        float acc = 0.f;
        #pragma unroll
        for (int it = 0; it < 4; ++it) {
            float4 e4 = er[lane + 64 * it];
            float4 o4 = ((const float4*)os)[lane + 64 * it];
            acc = fmaf(e4.x, o4.x, fmaf(e4.y, o4.y, fmaf(e4.z, o4.z, fmaf(e4.w, o4.w, acc))));
        }
        #pragma unroll
        for (int off = 32; off; off >>= 1) acc += __shfl_xor(acc, off, 64);
        if (lane == 0) ss[l] = acc;
    }
    __syncthreads();
    if (tid < 64) {
        float v = ss[tid];
        float mx = v;
        #pragma unroll
        for (int off = 32; off; off >>= 1) mx = fmaxf(mx, __shfl_xor(mx, off, 64));
        float e = expf(v - mx);
        float sum = e;
        #pragma unroll
        for (int off = 32; off; off >>= 1) sum += __shfl_xor(sum, off, 64);
        ws[tid] = e / sum;
    }
    __syncthreads();
    #pragma unroll
    for (int c = 0; c < 4; ++c) {
        const int col = tid + c * 256;
        float acc = 0.f;
        for (int l = 0; l < 64; ++l) acc = fmaf(ws[l], enc[(size_t)l * 1024 + col], acc);
        attn[(size_t)t * 2048 + 1024 + col] = acc;
    }
}

// ---------------------------------------------------------------------------
// Logits: logits[t][v] = dot(outs[t], W_fc[v]) + b_fc[v]
// Tiled fp32 GEMM: 64 v-rows x 64 t per block, K-chunks of 64. Grid 500.
// ---------------------------------------------------------------------------
__global__ __launch_bounds__(256) void k_logits(
    const float* __restrict__ outs,   // attn region [64][2048], first 1024 cols
    const float* __restrict__ W_fc,   // [32000][1024]
    const float* __restrict__ b_fc,   // [32000]
    float* __restrict__ logits)       // [64][32000]
{
    __shared__ float Wt[64 * 65];
    __shared__ float Ot[64 * 65];
    const int v0 = blockIdx.x * 64;
    const int tid = threadIdx.x;
    const int vi = tid & 15, ti = tid >> 4;
    float acc[4][4] = {};

    for (int kk = 0; kk < 1024; kk += 64) {
        __syncthreads();
        #pragma unroll
        for (int i = 0; i < 16; ++i) {
            int e = tid + i * 256;
            int vv = e >> 6, cc = e & 63;
            Wt[vv * 65 + cc] = W_fc[(size_t)(v0 + vv) * 1024 + kk + cc];
            Ot[vv * 65 + cc] = outs[(size_t)vv * 2048 + kk + cc];
        }
        __syncthreads();
        #pragma unroll 8
        for (int c = 0; c < 64; ++c) {
            float a[4], b[4];
            #pragma unroll
            for (int m = 0; m < 4; ++m) a[m] = Wt[(vi * 4 + m) * 65 + c];
            #pragma unroll
            for (int n = 0; n < 4; ++n) b[n] = Ot[(ti * 4 + n) * 65 + c];
            #pragma unroll
            for (int m = 0; m < 4; ++m)
                #pragma unroll
                for (int n = 0; n < 4; ++n)
                    acc[m][n] = fmaf(a[m], b[n], acc[m][n]);
        }
    }
    #pragma unroll
    for (int n = 0; n < 4; ++n) {
        const int t = ti * 4 + n;
        const int v = v0 + vi * 4;
        float4 o;
        o.x = acc[0][n] + b_fc[v + 0];
        o.y = acc[1][n] + b_fc[v + 1];
        o.z = acc[2][n] + b_fc[v + 2];
        o.w = acc[3][n] + b_fc[v + 3];
        *(float4*)(logits + (size_t)t * 32000 + v) = o;
    }
}

// ---------------------------------------------------------------------------
// Finalize: hT = [h0_63, h1_63], cT = [c0, c1]
// ---------------------------------------------------------------------------
__global__ __launch_bounds__(256) void k_finalize(
    const float* __restrict__ h0_hist,
    const float* __restrict__ attn,
    const float* __restrict__ c0s,
    const float* __restrict__ c1s,
    float* __restrict__ out_ht,
    float* __restrict__ out_ct)
{
    const int i = blockIdx.x * 256 + threadIdx.x;   // 0..2047
    if (i < 1024) {
        out_ht[i] = h0_hist[(size_t)63 * 1024 + i];
        out_ct[i] = c0s[i];
    } else {
        out_ht[i] = attn[(size_t)63 * 2048 + (i - 1024)];
        out_ct[i] = c1s[i - 1024];
    }
}

// ---------------------------------------------------------------------------
extern "C" void kernel_launch(void* const* d_in, const int* in_sizes, int n_in,
                              void* d_out, int out_size, void* d_ws, size_t ws_size,
                              hipStream_t stream)
{
    const float* dec  = (const float*)d_in[0];   // [1,64,512]
    const float* z    = (const float*)d_in[1];   // [1,512]
    const float* enc  = (const float*)d_in[2];   // [1,64,1024]
    const float* h0   = (const float*)d_in[3];   // [2,1,1024]
    const float* c0   = (const float*)d_in[4];   // [2,1,1024]
    const float* W_ih = (const float*)d_in[5];   // [2,4096,1024]
    const float* W_hh = (const float*)d_in[6];   // [2,4096,1024]
    const float* b_ih = (const float*)d_in[7];   // [2,4096]
    const float* b_hh = (const float*)d_in[8];   // [2,4096]
    const float* W_fc = (const float*)d_in[9];   // [32000,1024]
    const float* b_fc = (const float*)d_in[10];  // [32000]
    // d_in[11] = drop_prob (0, unused)

    float* out    = (float*)d_out;
    float* logits = out + OUT_LOGITS;
    float* attn   = out + OUT_ATTN;
    float* out_ht = out + OUT_HT;
    float* out_ct = out + OUT_CT;

    float* Gin0    = (float*)d_ws;            // 64*4096
    float* h0_hist = Gin0 + 64 * 4096;        // 64*1024
    float* c0s     = h0_hist + 64 * 1024;     // 1024
    float* c1s     = c0s + 1024;              // 1024

    k_input_gemm<<<256, 256, 0, stream>>>(dec, z, W_ih, b_ih, b_hh, Gin0);
    for (int k = 0; k <= 64; ++k)
        k_stage<<<512, 256, 0, stream>>>(k, W_ih, W_hh, b_ih, b_hh, h0, c0,
                                         Gin0, h0_hist, c0s, c1s, attn);
    k_attn<<<64, 256, 0, stream>>>(enc, attn);
    k_logits<<<500, 256, 0, stream>>>(attn, W_fc, b_fc, logits);
    k_finalize<<<8, 256, 0, stream>>>(h0_hist, attn, c0s, c1s, out_ht, out_ct);
}